// Round 4
// baseline (5438.510 us; speedup 1.0000x reference)
//
#include <hip/hip_runtime.h>

// ---------------------------------------------------------------------------
// GAT with heat-kernel diffusion preprocessing (GDC-style), MI355X fp32.
// CSR build -> 10x diffusion hops (readlane-broadcast gather) -> tiled GEMM1
// + logits -> online-softmax GAT agg (8hx8c) -> ELU -> GEMM2 + logits ->
// agg (1hx40c) -> log_softmax.
// ---------------------------------------------------------------------------

__global__ void init_node_kernel(int* deg, int* cursor, int n) {
    int i = blockIdx.x * 256 + threadIdx.x;
    if (i < n) { deg[i] = 1; cursor[i] = 0; }  // deg starts at 1 (self loop)
}

__global__ void edge_deg_kernel(const int* __restrict__ dst, int* deg, int E) {
    int e = blockIdx.x * 256 + threadIdx.x;
    if (e < E) atomicAdd(&deg[dst[e]], 1);
}

__global__ void alloc_kernel(const int* __restrict__ deg, float* dinv,
                             int* row_off, int* gcount, int n) {
    int i = blockIdx.x * 256 + threadIdx.x;
    if (i >= n) return;
    int dg = deg[i];
    dinv[i] = rsqrtf((float)dg);
    row_off[i] = atomicAdd(gcount, dg);
}

__global__ void scatter_kernel(const int* __restrict__ ei, const int* __restrict__ row_off,
                               int* cursor, const float* __restrict__ dinv,
                               int2* csr_pair, int E, int n) {
    int e = blockIdx.x * 256 + threadIdx.x;
    if (e >= E + n) return;
    int s, d;
    if (e < E) { s = ei[e]; d = ei[E + e]; } else { s = e - E; d = s; }
    int pos = atomicAdd(&cursor[d], 1);
    int slot = row_off[d] + pos;
    csr_pair[slot] = make_int2(s, __float_as_int(dinv[s] * dinv[d]));
}

// coefs[k][c] = exp(-t_c) * t_c^k / k!
__global__ void coef_kernel(const float* __restrict__ t, float* coefs) {
    int c = threadIdx.x;  // 128 threads
    float tc = t[c];
    float v = expf(-tc);
    coefs[c] = v;
    for (int k = 1; k <= 10; ++k) { v *= tc / (float)k; coefs[k * 128 + c] = v; }
}

__global__ void init_diff_kernel(const float4* __restrict__ x4, const float* __restrict__ coefs,
                                 float4* h4, float4* acc4, int total4) {
    int i = blockIdx.x * 256 + threadIdx.x;
    if (i >= total4) return;
    float4 xv = x4[i];
    h4[i] = xv;
    const float4 c = *(const float4*)&coefs[(i & 31) * 4];
    acc4[i] = make_float4(c.x * xv.x, c.y * xv.y, c.z * xv.z, c.w * xv.w);
}

// One wave per node, 2 channels/lane (float2). Neighbor (src,norm) broadcast
// via v_readlane (SALU), gather base from SGPR. 4 independent accumulators.
__global__ void hop_kernel(const int* __restrict__ row_off, const int* __restrict__ deg,
                           const int2* __restrict__ csr_pair,
                           const float2* __restrict__ h2, float2* __restrict__ h_next2,
                           float2* __restrict__ acc2, const float2* __restrict__ coefk2, int n) {
    int wid = (blockIdx.x << 2) + (threadIdx.x >> 6);
    int lane = threadIdx.x & 63;
    if (wid >= n) return;
    int off = row_off[wid];
    int cnt = deg[wid];
    float2 a0 = {0.f, 0.f}, a1 = {0.f, 0.f}, a2 = {0.f, 0.f}, a3 = {0.f, 0.f};
    for (int base = 0; base < cnt; base += 64) {
        int nb = min(64, cnt - base);
        int2 p = {0, 0};
        if (lane < nb) p = csr_pair[off + base + lane];
        int tt = 0;
        for (; tt + 3 < nb; tt += 4) {
            int s0 = __builtin_amdgcn_readlane(p.x, tt);
            int s1 = __builtin_amdgcn_readlane(p.x, tt + 1);
            int s2 = __builtin_amdgcn_readlane(p.x, tt + 2);
            int s3 = __builtin_amdgcn_readlane(p.x, tt + 3);
            float w0 = __int_as_float(__builtin_amdgcn_readlane(p.y, tt));
            float w1 = __int_as_float(__builtin_amdgcn_readlane(p.y, tt + 1));
            float w2 = __int_as_float(__builtin_amdgcn_readlane(p.y, tt + 2));
            float w3 = __int_as_float(__builtin_amdgcn_readlane(p.y, tt + 3));
            float2 h0 = h2[(size_t)s0 * 64 + lane];
            float2 h1v = h2[(size_t)s1 * 64 + lane];
            float2 h2v = h2[(size_t)s2 * 64 + lane];
            float2 h3 = h2[(size_t)s3 * 64 + lane];
            a0.x = fmaf(w0, h0.x, a0.x); a0.y = fmaf(w0, h0.y, a0.y);
            a1.x = fmaf(w1, h1v.x, a1.x); a1.y = fmaf(w1, h1v.y, a1.y);
            a2.x = fmaf(w2, h2v.x, a2.x); a2.y = fmaf(w2, h2v.y, a2.y);
            a3.x = fmaf(w3, h3.x, a3.x); a3.y = fmaf(w3, h3.y, a3.y);
        }
        for (; tt < nb; ++tt) {
            int s = __builtin_amdgcn_readlane(p.x, tt);
            float w = __int_as_float(__builtin_amdgcn_readlane(p.y, tt));
            float2 hv = h2[(size_t)s * 64 + lane];
            a0.x = fmaf(w, hv.x, a0.x); a0.y = fmaf(w, hv.y, a0.y);
        }
    }
    float2 s;
    s.x = (a0.x + a1.x) + (a2.x + a3.x);
    s.y = (a0.y + a1.y) + (a2.y + a3.y);
    size_t o = (size_t)wid * 64 + lane;
    h_next2[o] = s;
    float2 c = coefk2[lane];
    float2 av = acc2[o];
    av.x = fmaf(c.x, s.x, av.x);
    av.y = fmaf(c.y, s.y, av.y);
    acc2[o] = av;
}

// h1 = acc @ W1 (128x64) tiled: wave per 16 nodes, acc rows staged in LDS,
// W1 in LDS, k-chunks of 8 in registers. Fused per-head attention logits.
__global__ __launch_bounds__(256) void gemm1_kernel(
    const float* __restrict__ acc, const float* __restrict__ W1,
    const float* __restrict__ a_s, const float* __restrict__ a_d,
    float* __restrict__ h1, float* __restrict__ als, float* __restrict__ ald, int n) {
    __shared__ float Wl[128 * 64];
    __shared__ float Al[4][16 * 128];
    for (int i = threadIdx.x; i < 128 * 64; i += 256) Wl[i] = W1[i];
    int w = threadIdx.x >> 6;
    int lane = threadIdx.x & 63;
    int node0 = (blockIdx.x * 4 + w) * 16;
    // stage 16 acc rows (2048 floats = 512 float4) into this wave's LDS slab
    const float4* accv4 = (const float4*)acc;
    float4* Av4 = (float4*)Al[w];
#pragma unroll
    for (int i = 0; i < 8; ++i) {
        int f4 = i * 64 + lane;            // 0..511
        int g4 = node0 * 32 + f4;          // global float4 index
        float4 v = (g4 < n * 32) ? accv4[g4] : make_float4(0.f, 0.f, 0.f, 0.f);
        Av4[f4] = v;
    }
    __syncthreads();
    float sums[16];
#pragma unroll
    for (int nd = 0; nd < 16; ++nd) sums[nd] = 0.f;
#pragma unroll
    for (int kc = 0; kc < 16; ++kc) {
        float wr[8];
#pragma unroll
        for (int i = 0; i < 8; ++i) wr[i] = Wl[(kc * 8 + i) * 64 + lane];
#pragma unroll
        for (int nd = 0; nd < 16; ++nd) {
            float4 a = *(const float4*)&Al[w][nd * 128 + kc * 8];
            float4 b = *(const float4*)&Al[w][nd * 128 + kc * 8 + 4];
            float s = sums[nd];
            s = fmaf(wr[0], a.x, s); s = fmaf(wr[1], a.y, s);
            s = fmaf(wr[2], a.z, s); s = fmaf(wr[3], a.w, s);
            s = fmaf(wr[4], b.x, s); s = fmaf(wr[5], b.y, s);
            s = fmaf(wr[6], b.z, s); s = fmaf(wr[7], b.w, s);
            sums[nd] = s;
        }
    }
    float asv = a_s[lane], adv = a_d[lane];
#pragma unroll
    for (int nd = 0; nd < 16; ++nd) {
        int node = node0 + nd;
        if (node >= n) break;
        float sum = sums[nd];
        h1[(size_t)node * 64 + lane] = sum;
        float vs = sum * asv;
        float vd = sum * adv;
        vs += __shfl_xor(vs, 1); vs += __shfl_xor(vs, 2); vs += __shfl_xor(vs, 4);
        vd += __shfl_xor(vd, 1); vd += __shfl_xor(vd, 2); vd += __shfl_xor(vd, 4);
        if ((lane & 7) == 0) {
            als[(size_t)node * 8 + (lane >> 3)] = vs;
            ald[(size_t)node * 8 + (lane >> 3)] = vd;
        }
    }
}

// GAT layer-1 aggregation: online softmax per dst node, 8 heads x 8 channels.
__global__ void agg1_kernel(const int* __restrict__ row_off, const int* __restrict__ deg,
                            const int2* __restrict__ csr_pair,
                            const float* __restrict__ h1, const float* __restrict__ als,
                            const float* __restrict__ ald, const float* __restrict__ b1,
                            float* __restrict__ helu, int n) {
    int wid = (blockIdx.x << 2) + (threadIdx.x >> 6);
    int lane = threadIdx.x & 63;
    if (wid >= n) return;
    int head = lane >> 3;
    int off = row_off[wid];
    int cnt = deg[wid];
    float aldv = ald[(size_t)wid * 8 + head];
    float m = -1e30f, d = 0.f, accv = 0.f;
    for (int base = 0; base < cnt; base += 64) {
        int nb = min(64, cnt - base);
        int srcv = 0;
        if (lane < nb) srcv = csr_pair[off + base + lane].x;
        for (int tt = 0; tt < nb; ++tt) {
            int s = __builtin_amdgcn_readlane(srcv, tt);
            float e = als[(size_t)s * 8 + head] + aldv;
            e = e > 0.f ? e : 0.2f * e;  // leaky relu
            float hv = h1[(size_t)s * 64 + lane];
            float mn = fmaxf(m, e);
            float scale = __expf(m - mn);
            float p = __expf(e - mn);
            d = fmaf(d, scale, p);
            accv = fmaf(accv, scale, p * hv);
            m = mn;
        }
    }
    float outv = accv / d + b1[lane];
    outv = outv > 0.f ? outv : expm1f(outv);  // ELU
    helu[(size_t)wid * 64 + lane] = outv;
}

// h2 = helu @ W2 (64x40) tiled like gemm1; fused scalar attention logits.
__global__ __launch_bounds__(256) void gemm2_kernel(
    const float* __restrict__ helu, const float* __restrict__ W2,
    const float* __restrict__ a_s, const float* __restrict__ a_d,
    float* __restrict__ h2, float* __restrict__ als, float* __restrict__ ald, int n) {
    __shared__ float Wl[64 * 40];
    __shared__ float Al[4][16 * 64];
    for (int i = threadIdx.x; i < 64 * 40; i += 256) Wl[i] = W2[i];
    int w = threadIdx.x >> 6;
    int lane = threadIdx.x & 63;
    int node0 = (blockIdx.x * 4 + w) * 16;
    const float4* hv4 = (const float4*)helu;
    float4* Av4 = (float4*)Al[w];
#pragma unroll
    for (int i = 0; i < 4; ++i) {
        int f4 = i * 64 + lane;            // 0..255 (16 rows x 16 float4)
        int g4 = node0 * 16 + f4;
        float4 v = (g4 < n * 16) ? hv4[g4] : make_float4(0.f, 0.f, 0.f, 0.f);
        Av4[f4] = v;
    }
    __syncthreads();
    bool act = lane < 40;
    int li = act ? lane : 0;
    float sums[16];
#pragma unroll
    for (int nd = 0; nd < 16; ++nd) sums[nd] = 0.f;
#pragma unroll
    for (int kc = 0; kc < 8; ++kc) {
        float wr[8];
#pragma unroll
        for (int i = 0; i < 8; ++i) wr[i] = Wl[(kc * 8 + i) * 40 + li];
#pragma unroll
        for (int nd = 0; nd < 16; ++nd) {
            float4 a = *(const float4*)&Al[w][nd * 64 + kc * 8];
            float4 b = *(const float4*)&Al[w][nd * 64 + kc * 8 + 4];
            float s = sums[nd];
            s = fmaf(wr[0], a.x, s); s = fmaf(wr[1], a.y, s);
            s = fmaf(wr[2], a.z, s); s = fmaf(wr[3], a.w, s);
            s = fmaf(wr[4], b.x, s); s = fmaf(wr[5], b.y, s);
            s = fmaf(wr[6], b.z, s); s = fmaf(wr[7], b.w, s);
            sums[nd] = s;
        }
    }
    float asv = act ? a_s[lane] : 0.f;
    float adv = act ? a_d[lane] : 0.f;
#pragma unroll
    for (int nd = 0; nd < 16; ++nd) {
        int node = node0 + nd;
        if (node >= n) break;
        float sum = sums[nd];
        if (act) h2[(size_t)node * 40 + lane] = sum;
        float vs = act ? sum * asv : 0.f;
        float vd = act ? sum * adv : 0.f;
#pragma unroll
        for (int i = 32; i >= 1; i >>= 1) { vs += __shfl_xor(vs, i); vd += __shfl_xor(vd, i); }
        if (lane == 0) { als[node] = vs; ald[node] = vd; }
    }
}

// GAT layer-2 aggregation (1 head, 40 ch) + bias + log_softmax.
__global__ void agg2_kernel(const int* __restrict__ row_off, const int* __restrict__ deg,
                            const int2* __restrict__ csr_pair,
                            const float* __restrict__ h2, const float* __restrict__ als,
                            const float* __restrict__ ald, const float* __restrict__ b2,
                            float* __restrict__ out, int n) {
    int wid = (blockIdx.x << 2) + (threadIdx.x >> 6);
    int lane = threadIdx.x & 63;
    if (wid >= n) return;
    bool act = lane < 40;
    int li = act ? lane : 0;
    int off = row_off[wid];
    int cnt = deg[wid];
    float aldv = ald[wid];
    float m = -1e30f, d = 0.f, accv = 0.f;
    for (int base = 0; base < cnt; base += 64) {
        int nb = min(64, cnt - base);
        int srcv = 0;
        if (lane < nb) srcv = csr_pair[off + base + lane].x;
        for (int tt = 0; tt < nb; ++tt) {
            int s = __builtin_amdgcn_readlane(srcv, tt);
            float e = als[s] + aldv;
            e = e > 0.f ? e : 0.2f * e;
            float hv = h2[(size_t)s * 40 + li];
            float mn = fmaxf(m, e);
            float scale = __expf(m - mn);
            float p = __expf(e - mn);
            d = fmaf(d, scale, p);
            accv = fmaf(accv, scale, p * hv);
            m = mn;
        }
    }
    float o = accv / d + (act ? b2[lane] : 0.f);
    float vv = act ? o : -1e30f;
#pragma unroll
    for (int i = 32; i >= 1; i >>= 1) vv = fmaxf(vv, __shfl_xor(vv, i));
    float ex = act ? __expf(o - vv) : 0.f;
#pragma unroll
    for (int i = 32; i >= 1; i >>= 1) ex += __shfl_xor(ex, i);
    if (act) out[(size_t)wid * 40 + lane] = o - vv - logf(ex);
}

extern "C" void kernel_launch(void* const* d_in, const int* in_sizes, int n_in,
                              void* d_out, int out_size, void* d_ws, size_t ws_size,
                              hipStream_t stream) {
    const float* x    = (const float*)d_in[0];
    const int*   ei   = (const int*)d_in[1];
    const float* t    = (const float*)d_in[2];
    const float* W1   = (const float*)d_in[3];
    const float* a_s1 = (const float*)d_in[4];
    const float* a_d1 = (const float*)d_in[5];
    const float* b1   = (const float*)d_in[6];
    const float* W2   = (const float*)d_in[7];
    const float* a_s2 = (const float*)d_in[8];
    const float* a_d2 = (const float*)d_in[9];
    const float* b2   = (const float*)d_in[10];
    float* out = (float*)d_out;

    const int N = in_sizes[0] / 128;
    const int E = in_sizes[1] / 2;

    char* w = (char*)d_ws;
    auto carve = [&](size_t bytes) {
        void* p = (void*)w;
        w += (bytes + 255) & ~(size_t)255;
        return p;
    };
    int*   deg      = (int*)carve((size_t)N * 4);
    int*   cursor   = (int*)carve((size_t)N * 4);
    int*   row_off  = (int*)carve((size_t)N * 4);
    int*   gcount   = (int*)carve(256);
    float* dinv     = (float*)carve((size_t)N * 4);
    int2*  csr_pair = (int2*)carve((size_t)(E + N) * 8);
    float* coefs    = (float*)carve(11 * 128 * 4);
    float* als1     = (float*)carve((size_t)N * 8 * 4);
    float* ald1     = (float*)carve((size_t)N * 8 * 4);
    float* als2     = (float*)carve((size_t)N * 4);
    float* ald2     = (float*)carve((size_t)N * 4);
    float* hA       = (float*)carve((size_t)N * 128 * 4);
    float* hB       = (float*)carve((size_t)N * 128 * 4);
    float* acc      = (float*)carve((size_t)N * 128 * 4);
    // reuse diffusion ping-pong buffers after diffusion:
    float* h1   = hA;                     // [N,64]
    float* helu = hB;                     // [N,64]
    float* h2   = hA + (size_t)N * 64;    // [N,40] (disjoint from h1)

    dim3 blk(256);
    int gN = (N + 255) / 256;
    int gE = (E + 255) / 256;
    int gEN = (E + N + 255) / 256;
    int gW = (N + 3) / 4;        // one wave per node, 4 waves/block
    int gT = (N + 63) / 64;      // wave per 16 nodes, 4 waves/block

    init_node_kernel<<<gN, blk, 0, stream>>>(deg, cursor, N);
    hipMemsetAsync(gcount, 0, 4, stream);
    edge_deg_kernel<<<gE, blk, 0, stream>>>(ei + E, deg, E);
    alloc_kernel<<<gN, blk, 0, stream>>>(deg, dinv, row_off, gcount, N);
    scatter_kernel<<<gEN, blk, 0, stream>>>(ei, row_off, cursor, dinv, csr_pair, E, N);
    coef_kernel<<<1, 128, 0, stream>>>(t, coefs);
    init_diff_kernel<<<(N * 32 + 255) / 256, blk, 0, stream>>>(
        (const float4*)x, coefs, (float4*)hA, (float4*)acc, N * 32);

    float* hc = hA;
    float* hn = hB;
    for (int k = 1; k <= 10; ++k) {
        hop_kernel<<<gW, blk, 0, stream>>>(row_off, deg, csr_pair,
                                           (const float2*)hc, (float2*)hn, (float2*)acc,
                                           (const float2*)(coefs + k * 128), N);
        float* tmp = hc; hc = hn; hn = tmp;
    }

    gemm1_kernel<<<gT, blk, 0, stream>>>(acc, W1, a_s1, a_d1, h1, als1, ald1, N);
    agg1_kernel<<<gW, blk, 0, stream>>>(row_off, deg, csr_pair, h1, als1, ald1, b1, helu, N);
    gemm2_kernel<<<gT, blk, 0, stream>>>(helu, W2, a_s2, a_d2, h2, als2, ald2, N);
    agg2_kernel<<<gW, blk, 0, stream>>>(row_off, deg, csr_pair, h2, als2, ald2, b2, out, N);
}

// Round 6
// 1992.388 us; speedup vs baseline: 2.7296x; 2.7296x over previous
//
#include <hip/hip_runtime.h>

// ---------------------------------------------------------------------------
// GAT with heat-kernel diffusion preprocessing (GDC-style), MI355X fp32.
// CSR build -> 10x diffusion hops (readlane-broadcast gather) -> tiled GEMM1
// + logits -> online-softmax GAT agg (8hx8c) -> ELU -> GEMM2 + logits ->
// agg (1hx40c) -> log_softmax.
// Round 5: fix gemm spill — kc loops get `#pragma unroll 1` (full unroll had
// software-pipelined 256 iterations -> 256 VGPR + GBs of scratch traffic).
// ---------------------------------------------------------------------------

__global__ void init_node_kernel(int* deg, int* cursor, int n) {
    int i = blockIdx.x * 256 + threadIdx.x;
    if (i < n) { deg[i] = 1; cursor[i] = 0; }  // deg starts at 1 (self loop)
}

__global__ void edge_deg_kernel(const int* __restrict__ dst, int* deg, int E) {
    int e = blockIdx.x * 256 + threadIdx.x;
    if (e < E) atomicAdd(&deg[dst[e]], 1);
}

__global__ void alloc_kernel(const int* __restrict__ deg, float* dinv,
                             int* row_off, int* gcount, int n) {
    int i = blockIdx.x * 256 + threadIdx.x;
    if (i >= n) return;
    int dg = deg[i];
    dinv[i] = rsqrtf((float)dg);
    row_off[i] = atomicAdd(gcount, dg);
}

__global__ void scatter_kernel(const int* __restrict__ ei, const int* __restrict__ row_off,
                               int* cursor, const float* __restrict__ dinv,
                               int2* csr_pair, int E, int n) {
    int e = blockIdx.x * 256 + threadIdx.x;
    if (e >= E + n) return;
    int s, d;
    if (e < E) { s = ei[e]; d = ei[E + e]; } else { s = e - E; d = s; }
    int pos = atomicAdd(&cursor[d], 1);
    int slot = row_off[d] + pos;
    csr_pair[slot] = make_int2(s, __float_as_int(dinv[s] * dinv[d]));
}

// coefs[k][c] = exp(-t_c) * t_c^k / k!
__global__ void coef_kernel(const float* __restrict__ t, float* coefs) {
    int c = threadIdx.x;  // 128 threads
    float tc = t[c];
    float v = expf(-tc);
    coefs[c] = v;
    for (int k = 1; k <= 10; ++k) { v *= tc / (float)k; coefs[k * 128 + c] = v; }
}

__global__ void init_diff_kernel(const float4* __restrict__ x4, const float* __restrict__ coefs,
                                 float4* h4, float4* acc4, int total4) {
    int i = blockIdx.x * 256 + threadIdx.x;
    if (i >= total4) return;
    float4 xv = x4[i];
    h4[i] = xv;
    const float4 c = *(const float4*)&coefs[(i & 31) * 4];
    acc4[i] = make_float4(c.x * xv.x, c.y * xv.y, c.z * xv.z, c.w * xv.w);
}

// One wave per node, 2 channels/lane (float2). Neighbor (src,norm) broadcast
// via v_readlane (SALU), gather base from SGPR. 4 independent accumulators.
__global__ void hop_kernel(const int* __restrict__ row_off, const int* __restrict__ deg,
                           const int2* __restrict__ csr_pair,
                           const float2* __restrict__ h2, float2* __restrict__ h_next2,
                           float2* __restrict__ acc2, const float2* __restrict__ coefk2, int n) {
    int wid = (blockIdx.x << 2) + (threadIdx.x >> 6);
    int lane = threadIdx.x & 63;
    if (wid >= n) return;
    int off = row_off[wid];
    int cnt = deg[wid];
    float2 a0 = {0.f, 0.f}, a1 = {0.f, 0.f}, a2 = {0.f, 0.f}, a3 = {0.f, 0.f};
    for (int base = 0; base < cnt; base += 64) {
        int nb = min(64, cnt - base);
        int2 p = {0, 0};
        if (lane < nb) p = csr_pair[off + base + lane];
        int tt = 0;
        for (; tt + 3 < nb; tt += 4) {
            int s0 = __builtin_amdgcn_readlane(p.x, tt);
            int s1 = __builtin_amdgcn_readlane(p.x, tt + 1);
            int s2 = __builtin_amdgcn_readlane(p.x, tt + 2);
            int s3 = __builtin_amdgcn_readlane(p.x, tt + 3);
            float w0 = __int_as_float(__builtin_amdgcn_readlane(p.y, tt));
            float w1 = __int_as_float(__builtin_amdgcn_readlane(p.y, tt + 1));
            float w2 = __int_as_float(__builtin_amdgcn_readlane(p.y, tt + 2));
            float w3 = __int_as_float(__builtin_amdgcn_readlane(p.y, tt + 3));
            float2 h0 = h2[(size_t)s0 * 64 + lane];
            float2 h1v = h2[(size_t)s1 * 64 + lane];
            float2 h2v = h2[(size_t)s2 * 64 + lane];
            float2 h3 = h2[(size_t)s3 * 64 + lane];
            a0.x = fmaf(w0, h0.x, a0.x); a0.y = fmaf(w0, h0.y, a0.y);
            a1.x = fmaf(w1, h1v.x, a1.x); a1.y = fmaf(w1, h1v.y, a1.y);
            a2.x = fmaf(w2, h2v.x, a2.x); a2.y = fmaf(w2, h2v.y, a2.y);
            a3.x = fmaf(w3, h3.x, a3.x); a3.y = fmaf(w3, h3.y, a3.y);
        }
        for (; tt < nb; ++tt) {
            int s = __builtin_amdgcn_readlane(p.x, tt);
            float w = __int_as_float(__builtin_amdgcn_readlane(p.y, tt));
            float2 hv = h2[(size_t)s * 64 + lane];
            a0.x = fmaf(w, hv.x, a0.x); a0.y = fmaf(w, hv.y, a0.y);
        }
    }
    float2 s;
    s.x = (a0.x + a1.x) + (a2.x + a3.x);
    s.y = (a0.y + a1.y) + (a2.y + a3.y);
    size_t o = (size_t)wid * 64 + lane;
    h_next2[o] = s;
    float2 c = coefk2[lane];
    float2 av = acc2[o];
    av.x = fmaf(c.x, s.x, av.x);
    av.y = fmaf(c.y, s.y, av.y);
    acc2[o] = av;
}

// h1 = acc @ W1 (128x64) tiled: wave per 16 nodes, acc rows staged in LDS,
// W1 in LDS, k-chunks of 8 in registers. Fused per-head attention logits.
// kc loop is unroll(1): full unroll software-pipelined 256 iterations of
// LDS b128 loads -> 256 VGPR + scratch spill (round-4 regression).
__global__ __launch_bounds__(256) void gemm1_kernel(
    const float* __restrict__ acc, const float* __restrict__ W1,
    const float* __restrict__ a_s, const float* __restrict__ a_d,
    float* __restrict__ h1, float* __restrict__ als, float* __restrict__ ald, int n) {
    __shared__ float Wl[128 * 64];
    __shared__ float Al[4][16 * 128];
    for (int i = threadIdx.x; i < 128 * 64; i += 256) Wl[i] = W1[i];
    int w = threadIdx.x >> 6;
    int lane = threadIdx.x & 63;
    int node0 = (blockIdx.x * 4 + w) * 16;
    // stage 16 acc rows (2048 floats = 512 float4) into this wave's LDS slab
    const float4* accv4 = (const float4*)acc;
    float4* Av4 = (float4*)Al[w];
#pragma unroll
    for (int i = 0; i < 8; ++i) {
        int f4 = i * 64 + lane;            // 0..511
        int g4 = node0 * 32 + f4;          // global float4 index
        float4 v = (g4 < n * 32) ? accv4[g4] : make_float4(0.f, 0.f, 0.f, 0.f);
        Av4[f4] = v;
    }
    __syncthreads();
    float sums[16];
#pragma unroll
    for (int nd = 0; nd < 16; ++nd) sums[nd] = 0.f;
#pragma unroll 1
    for (int kc = 0; kc < 16; ++kc) {
        float wr[8];
#pragma unroll
        for (int i = 0; i < 8; ++i) wr[i] = Wl[(kc * 8 + i) * 64 + lane];
#pragma unroll
        for (int nd = 0; nd < 16; ++nd) {
            float4 a = *(const float4*)&Al[w][nd * 128 + kc * 8];
            float4 b = *(const float4*)&Al[w][nd * 128 + kc * 8 + 4];
            float s = sums[nd];
            s = fmaf(wr[0], a.x, s); s = fmaf(wr[1], a.y, s);
            s = fmaf(wr[2], a.z, s); s = fmaf(wr[3], a.w, s);
            s = fmaf(wr[4], b.x, s); s = fmaf(wr[5], b.y, s);
            s = fmaf(wr[6], b.z, s); s = fmaf(wr[7], b.w, s);
            sums[nd] = s;
        }
    }
    float asv = a_s[lane], adv = a_d[lane];
#pragma unroll
    for (int nd = 0; nd < 16; ++nd) {
        int node = node0 + nd;
        if (node >= n) break;
        float sum = sums[nd];
        h1[(size_t)node * 64 + lane] = sum;
        float vs = sum * asv;
        float vd = sum * adv;
        vs += __shfl_xor(vs, 1); vs += __shfl_xor(vs, 2); vs += __shfl_xor(vs, 4);
        vd += __shfl_xor(vd, 1); vd += __shfl_xor(vd, 2); vd += __shfl_xor(vd, 4);
        if ((lane & 7) == 0) {
            als[(size_t)node * 8 + (lane >> 3)] = vs;
            ald[(size_t)node * 8 + (lane >> 3)] = vd;
        }
    }
}

// GAT layer-1 aggregation: online softmax per dst node, 8 heads x 8 channels.
__global__ void agg1_kernel(const int* __restrict__ row_off, const int* __restrict__ deg,
                            const int2* __restrict__ csr_pair,
                            const float* __restrict__ h1, const float* __restrict__ als,
                            const float* __restrict__ ald, const float* __restrict__ b1,
                            float* __restrict__ helu, int n) {
    int wid = (blockIdx.x << 2) + (threadIdx.x >> 6);
    int lane = threadIdx.x & 63;
    if (wid >= n) return;
    int head = lane >> 3;
    int off = row_off[wid];
    int cnt = deg[wid];
    float aldv = ald[(size_t)wid * 8 + head];
    float m = -1e30f, d = 0.f, accv = 0.f;
    for (int base = 0; base < cnt; base += 64) {
        int nb = min(64, cnt - base);
        int srcv = 0;
        if (lane < nb) srcv = csr_pair[off + base + lane].x;
        for (int tt = 0; tt < nb; ++tt) {
            int s = __builtin_amdgcn_readlane(srcv, tt);
            float e = als[(size_t)s * 8 + head] + aldv;
            e = e > 0.f ? e : 0.2f * e;  // leaky relu
            float hv = h1[(size_t)s * 64 + lane];
            float mn = fmaxf(m, e);
            float scale = __expf(m - mn);
            float p = __expf(e - mn);
            d = fmaf(d, scale, p);
            accv = fmaf(accv, scale, p * hv);
            m = mn;
        }
    }
    float outv = accv / d + b1[lane];
    outv = outv > 0.f ? outv : expm1f(outv);  // ELU
    helu[(size_t)wid * 64 + lane] = outv;
}

// h2 = helu @ W2 (64x40) tiled like gemm1; fused scalar attention logits.
__global__ __launch_bounds__(256) void gemm2_kernel(
    const float* __restrict__ helu, const float* __restrict__ W2,
    const float* __restrict__ a_s, const float* __restrict__ a_d,
    float* __restrict__ h2, float* __restrict__ als, float* __restrict__ ald, int n) {
    __shared__ float Wl[64 * 40];
    __shared__ float Al[4][16 * 64];
    for (int i = threadIdx.x; i < 64 * 40; i += 256) Wl[i] = W2[i];
    int w = threadIdx.x >> 6;
    int lane = threadIdx.x & 63;
    int node0 = (blockIdx.x * 4 + w) * 16;
    const float4* hv4 = (const float4*)helu;
    float4* Av4 = (float4*)Al[w];
#pragma unroll
    for (int i = 0; i < 4; ++i) {
        int f4 = i * 64 + lane;            // 0..255 (16 rows x 16 float4)
        int g4 = node0 * 16 + f4;
        float4 v = (g4 < n * 16) ? hv4[g4] : make_float4(0.f, 0.f, 0.f, 0.f);
        Av4[f4] = v;
    }
    __syncthreads();
    bool act = lane < 40;
    int li = act ? lane : 0;
    float sums[16];
#pragma unroll
    for (int nd = 0; nd < 16; ++nd) sums[nd] = 0.f;
#pragma unroll 1
    for (int kc = 0; kc < 8; ++kc) {
        float wr[8];
#pragma unroll
        for (int i = 0; i < 8; ++i) wr[i] = Wl[(kc * 8 + i) * 40 + li];
#pragma unroll
        for (int nd = 0; nd < 16; ++nd) {
            float4 a = *(const float4*)&Al[w][nd * 64 + kc * 8];
            float4 b = *(const float4*)&Al[w][nd * 64 + kc * 8 + 4];
            float s = sums[nd];
            s = fmaf(wr[0], a.x, s); s = fmaf(wr[1], a.y, s);
            s = fmaf(wr[2], a.z, s); s = fmaf(wr[3], a.w, s);
            s = fmaf(wr[4], b.x, s); s = fmaf(wr[5], b.y, s);
            s = fmaf(wr[6], b.z, s); s = fmaf(wr[7], b.w, s);
            sums[nd] = s;
        }
    }
    float asv = act ? a_s[lane] : 0.f;
    float adv = act ? a_d[lane] : 0.f;
#pragma unroll
    for (int nd = 0; nd < 16; ++nd) {
        int node = node0 + nd;
        if (node >= n) break;
        float sum = sums[nd];
        if (act) h2[(size_t)node * 40 + lane] = sum;
        float vs = act ? sum * asv : 0.f;
        float vd = act ? sum * adv : 0.f;
#pragma unroll
        for (int i = 32; i >= 1; i >>= 1) { vs += __shfl_xor(vs, i); vd += __shfl_xor(vd, i); }
        if (lane == 0) { als[node] = vs; ald[node] = vd; }
    }
}

// GAT layer-2 aggregation (1 head, 40 ch) + bias + log_softmax.
__global__ void agg2_kernel(const int* __restrict__ row_off, const int* __restrict__ deg,
                            const int2* __restrict__ csr_pair,
                            const float* __restrict__ h2, const float* __restrict__ als,
                            const float* __restrict__ ald, const float* __restrict__ b2,
                            float* __restrict__ out, int n) {
    int wid = (blockIdx.x << 2) + (threadIdx.x >> 6);
    int lane = threadIdx.x & 63;
    if (wid >= n) return;
    bool act = lane < 40;
    int li = act ? lane : 0;
    int off = row_off[wid];
    int cnt = deg[wid];
    float aldv = ald[wid];
    float m = -1e30f, d = 0.f, accv = 0.f;
    for (int base = 0; base < cnt; base += 64) {
        int nb = min(64, cnt - base);
        int srcv = 0;
        if (lane < nb) srcv = csr_pair[off + base + lane].x;
        for (int tt = 0; tt < nb; ++tt) {
            int s = __builtin_amdgcn_readlane(srcv, tt);
            float e = als[s] + aldv;
            e = e > 0.f ? e : 0.2f * e;
            float hv = h2[(size_t)s * 40 + li];
            float mn = fmaxf(m, e);
            float scale = __expf(m - mn);
            float p = __expf(e - mn);
            d = fmaf(d, scale, p);
            accv = fmaf(accv, scale, p * hv);
            m = mn;
        }
    }
    float o = accv / d + (act ? b2[lane] : 0.f);
    float vv = act ? o : -1e30f;
#pragma unroll
    for (int i = 32; i >= 1; i >>= 1) vv = fmaxf(vv, __shfl_xor(vv, i));
    float ex = act ? __expf(o - vv) : 0.f;
#pragma unroll
    for (int i = 32; i >= 1; i >>= 1) ex += __shfl_xor(ex, i);
    if (act) out[(size_t)wid * 40 + lane] = o - vv - logf(ex);
}

extern "C" void kernel_launch(void* const* d_in, const int* in_sizes, int n_in,
                              void* d_out, int out_size, void* d_ws, size_t ws_size,
                              hipStream_t stream) {
    const float* x    = (const float*)d_in[0];
    const int*   ei   = (const int*)d_in[1];
    const float* t    = (const float*)d_in[2];
    const float* W1   = (const float*)d_in[3];
    const float* a_s1 = (const float*)d_in[4];
    const float* a_d1 = (const float*)d_in[5];
    const float* b1   = (const float*)d_in[6];
    const float* W2   = (const float*)d_in[7];
    const float* a_s2 = (const float*)d_in[8];
    const float* a_d2 = (const float*)d_in[9];
    const float* b2   = (const float*)d_in[10];
    float* out = (float*)d_out;

    const int N = in_sizes[0] / 128;
    const int E = in_sizes[1] / 2;

    char* w = (char*)d_ws;
    auto carve = [&](size_t bytes) {
        void* p = (void*)w;
        w += (bytes + 255) & ~(size_t)255;
        return p;
    };
    int*   deg      = (int*)carve((size_t)N * 4);
    int*   cursor   = (int*)carve((size_t)N * 4);
    int*   row_off  = (int*)carve((size_t)N * 4);
    int*   gcount   = (int*)carve(256);
    float* dinv     = (float*)carve((size_t)N * 4);
    int2*  csr_pair = (int2*)carve((size_t)(E + N) * 8);
    float* coefs    = (float*)carve(11 * 128 * 4);
    float* als1     = (float*)carve((size_t)N * 8 * 4);
    float* ald1     = (float*)carve((size_t)N * 8 * 4);
    float* als2     = (float*)carve((size_t)N * 4);
    float* ald2     = (float*)carve((size_t)N * 4);
    float* hA       = (float*)carve((size_t)N * 128 * 4);
    float* hB       = (float*)carve((size_t)N * 128 * 4);
    float* acc      = (float*)carve((size_t)N * 128 * 4);
    // reuse diffusion ping-pong buffers after diffusion:
    float* h1   = hA;                     // [N,64]
    float* helu = hB;                     // [N,64]
    float* h2   = hA + (size_t)N * 64;    // [N,40] (disjoint from h1)

    dim3 blk(256);
    int gN = (N + 255) / 256;
    int gE = (E + 255) / 256;
    int gEN = (E + N + 255) / 256;
    int gW = (N + 3) / 4;        // one wave per node, 4 waves/block
    int gT = (N + 63) / 64;      // wave per 16 nodes, 4 waves/block

    init_node_kernel<<<gN, blk, 0, stream>>>(deg, cursor, N);
    hipMemsetAsync(gcount, 0, 4, stream);
    edge_deg_kernel<<<gE, blk, 0, stream>>>(ei + E, deg, E);
    alloc_kernel<<<gN, blk, 0, stream>>>(deg, dinv, row_off, gcount, N);
    scatter_kernel<<<gEN, blk, 0, stream>>>(ei, row_off, cursor, dinv, csr_pair, E, N);
    coef_kernel<<<1, 128, 0, stream>>>(t, coefs);
    init_diff_kernel<<<(N * 32 + 255) / 256, blk, 0, stream>>>(
        (const float4*)x, coefs, (float4*)hA, (float4*)acc, N * 32);

    float* hc = hA;
    float* hn = hB;
    for (int k = 1; k <= 10; ++k) {
        hop_kernel<<<gW, blk, 0, stream>>>(row_off, deg, csr_pair,
                                           (const float2*)hc, (float2*)hn, (float2*)acc,
                                           (const float2*)(coefs + k * 128), N);
        float* tmp = hc; hc = hn; hn = tmp;
    }

    gemm1_kernel<<<gT, blk, 0, stream>>>(acc, W1, a_s1, a_d1, h1, als1, ald1, N);
    agg1_kernel<<<gW, blk, 0, stream>>>(row_off, deg, csr_pair, h1, als1, ald1, b1, helu, N);
    gemm2_kernel<<<gT, blk, 0, stream>>>(helu, W2, a_s2, a_d2, h2, als2, ald2, N);
    agg2_kernel<<<gW, blk, 0, stream>>>(row_off, deg, csr_pair, h2, als2, ald2, b2, out, N);
}

// Round 7
// 1409.693 us; speedup vs baseline: 3.8579x; 1.4133x over previous
//
#include <hip/hip_runtime.h>
#include <hip/hip_bf16.h>

// ---------------------------------------------------------------------------
// GAT with heat-kernel diffusion preprocessing (GDC-style), MI355X.
// CSR build -> 10x diffusion hops (bf16 h storage, readlane-broadcast gather,
// fp32 accumulate) -> tiled GEMM1 + logits -> online-softmax GAT agg (8hx8c)
// -> ELU -> GEMM2 + logits -> agg (1hx40c) -> log_softmax.
// Round 7: h ping-pong buffers in bf16 — halves the dominant hop gather
// traffic (hop was 69% of runtime at 50% HBM peak). acc stays fp32.
// ---------------------------------------------------------------------------

static __device__ __forceinline__ unsigned pack_bf16x2(float a, float b) {
    __hip_bfloat162 p(__float2bfloat16(a), __float2bfloat16(b));  // a in low 16
    return *reinterpret_cast<unsigned*>(&p);
}

__global__ void init_node_kernel(int* deg, int* cursor, int n) {
    int i = blockIdx.x * 256 + threadIdx.x;
    if (i < n) { deg[i] = 1; cursor[i] = 0; }  // deg starts at 1 (self loop)
}

__global__ void edge_deg_kernel(const int* __restrict__ dst, int* deg, int E) {
    int e = blockIdx.x * 256 + threadIdx.x;
    if (e < E) atomicAdd(&deg[dst[e]], 1);
}

__global__ void alloc_kernel(const int* __restrict__ deg, float* dinv,
                             int* row_off, int* gcount, int n) {
    int i = blockIdx.x * 256 + threadIdx.x;
    if (i >= n) return;
    int dg = deg[i];
    dinv[i] = rsqrtf((float)dg);
    row_off[i] = atomicAdd(gcount, dg);
}

__global__ void scatter_kernel(const int* __restrict__ ei, const int* __restrict__ row_off,
                               int* cursor, const float* __restrict__ dinv,
                               int2* csr_pair, int E, int n) {
    int e = blockIdx.x * 256 + threadIdx.x;
    if (e >= E + n) return;
    int s, d;
    if (e < E) { s = ei[e]; d = ei[E + e]; } else { s = e - E; d = s; }
    int pos = atomicAdd(&cursor[d], 1);
    int slot = row_off[d] + pos;
    csr_pair[slot] = make_int2(s, __float_as_int(dinv[s] * dinv[d]));
}

// coefs[k][c] = exp(-t_c) * t_c^k / k!
__global__ void coef_kernel(const float* __restrict__ t, float* coefs) {
    int c = threadIdx.x;  // 128 threads
    float tc = t[c];
    float v = expf(-tc);
    coefs[c] = v;
    for (int k = 1; k <= 10; ++k) { v *= tc / (float)k; coefs[k * 128 + c] = v; }
}

// thread handles 4 channels: h (bf16) packed as uint2, acc fp32 float4.
__global__ void init_diff_kernel(const float4* __restrict__ x4, const float* __restrict__ coefs,
                                 uint2* __restrict__ h, float4* __restrict__ acc4, int total4) {
    int i = blockIdx.x * 256 + threadIdx.x;
    if (i >= total4) return;
    float4 xv = x4[i];
    h[i] = make_uint2(pack_bf16x2(xv.x, xv.y), pack_bf16x2(xv.z, xv.w));
    const float4 c = *(const float4*)&coefs[(i & 31) * 4];
    acc4[i] = make_float4(c.x * xv.x, c.y * xv.y, c.z * xv.z, c.w * xv.w);
}

// One wave per node, 2 channels/lane (one packed bf16x2 uint). Neighbor
// (src,norm) broadcast via v_readlane; 4 independent accumulators (fp32).
__global__ void hop_kernel(const int* __restrict__ row_off, const int* __restrict__ deg,
                           const int2* __restrict__ csr_pair,
                           const unsigned* __restrict__ h, unsigned* __restrict__ h_next,
                           float2* __restrict__ acc2, const float2* __restrict__ coefk2,
                           int n, int write_h) {
    int wid = (blockIdx.x << 2) + (threadIdx.x >> 6);
    int lane = threadIdx.x & 63;
    if (wid >= n) return;
    int off = row_off[wid];
    int cnt = deg[wid];
    float2 a0 = {0.f, 0.f}, a1 = {0.f, 0.f}, a2 = {0.f, 0.f}, a3 = {0.f, 0.f};
    for (int base = 0; base < cnt; base += 64) {
        int nb = min(64, cnt - base);
        int2 p = {0, 0};
        if (lane < nb) p = csr_pair[off + base + lane];
        int tt = 0;
        for (; tt + 3 < nb; tt += 4) {
            int s0 = __builtin_amdgcn_readlane(p.x, tt);
            int s1 = __builtin_amdgcn_readlane(p.x, tt + 1);
            int s2 = __builtin_amdgcn_readlane(p.x, tt + 2);
            int s3 = __builtin_amdgcn_readlane(p.x, tt + 3);
            float w0 = __int_as_float(__builtin_amdgcn_readlane(p.y, tt));
            float w1 = __int_as_float(__builtin_amdgcn_readlane(p.y, tt + 1));
            float w2 = __int_as_float(__builtin_amdgcn_readlane(p.y, tt + 2));
            float w3 = __int_as_float(__builtin_amdgcn_readlane(p.y, tt + 3));
            unsigned u0 = h[(size_t)s0 * 64 + lane];
            unsigned u1 = h[(size_t)s1 * 64 + lane];
            unsigned u2 = h[(size_t)s2 * 64 + lane];
            unsigned u3 = h[(size_t)s3 * 64 + lane];
            a0.x = fmaf(w0, __uint_as_float(u0 << 16), a0.x);
            a0.y = fmaf(w0, __uint_as_float(u0 & 0xffff0000u), a0.y);
            a1.x = fmaf(w1, __uint_as_float(u1 << 16), a1.x);
            a1.y = fmaf(w1, __uint_as_float(u1 & 0xffff0000u), a1.y);
            a2.x = fmaf(w2, __uint_as_float(u2 << 16), a2.x);
            a2.y = fmaf(w2, __uint_as_float(u2 & 0xffff0000u), a2.y);
            a3.x = fmaf(w3, __uint_as_float(u3 << 16), a3.x);
            a3.y = fmaf(w3, __uint_as_float(u3 & 0xffff0000u), a3.y);
        }
        for (; tt < nb; ++tt) {
            int s = __builtin_amdgcn_readlane(p.x, tt);
            float w = __int_as_float(__builtin_amdgcn_readlane(p.y, tt));
            unsigned u = h[(size_t)s * 64 + lane];
            a0.x = fmaf(w, __uint_as_float(u << 16), a0.x);
            a0.y = fmaf(w, __uint_as_float(u & 0xffff0000u), a0.y);
        }
    }
    float2 s;
    s.x = (a0.x + a1.x) + (a2.x + a3.x);
    s.y = (a0.y + a1.y) + (a2.y + a3.y);
    size_t o = (size_t)wid * 64 + lane;
    if (write_h) h_next[o] = pack_bf16x2(s.x, s.y);
    float2 c = coefk2[lane];
    float2 av = acc2[o];
    av.x = fmaf(c.x, s.x, av.x);
    av.y = fmaf(c.y, s.y, av.y);
    acc2[o] = av;
}

// h1 = acc @ W1 (128x64) tiled: wave per 16 nodes, acc rows staged in LDS,
// W1 in LDS, k-chunks of 8 in registers. Fused per-head attention logits.
// kc loop unroll(1): full unroll spilled to scratch (round-4 regression).
__global__ __launch_bounds__(256) void gemm1_kernel(
    const float* __restrict__ acc, const float* __restrict__ W1,
    const float* __restrict__ a_s, const float* __restrict__ a_d,
    float* __restrict__ h1, float* __restrict__ als, float* __restrict__ ald, int n) {
    __shared__ float Wl[128 * 64];
    __shared__ float Al[4][16 * 128];
    for (int i = threadIdx.x; i < 128 * 64; i += 256) Wl[i] = W1[i];
    int w = threadIdx.x >> 6;
    int lane = threadIdx.x & 63;
    int node0 = (blockIdx.x * 4 + w) * 16;
    const float4* accv4 = (const float4*)acc;
    float4* Av4 = (float4*)Al[w];
#pragma unroll
    for (int i = 0; i < 8; ++i) {
        int f4 = i * 64 + lane;            // 0..511
        int g4 = node0 * 32 + f4;          // global float4 index
        float4 v = (g4 < n * 32) ? accv4[g4] : make_float4(0.f, 0.f, 0.f, 0.f);
        Av4[f4] = v;
    }
    __syncthreads();
    float sums[16];
#pragma unroll
    for (int nd = 0; nd < 16; ++nd) sums[nd] = 0.f;
#pragma unroll 1
    for (int kc = 0; kc < 16; ++kc) {
        float wr[8];
#pragma unroll
        for (int i = 0; i < 8; ++i) wr[i] = Wl[(kc * 8 + i) * 64 + lane];
#pragma unroll
        for (int nd = 0; nd < 16; ++nd) {
            float4 a = *(const float4*)&Al[w][nd * 128 + kc * 8];
            float4 b = *(const float4*)&Al[w][nd * 128 + kc * 8 + 4];
            float s = sums[nd];
            s = fmaf(wr[0], a.x, s); s = fmaf(wr[1], a.y, s);
            s = fmaf(wr[2], a.z, s); s = fmaf(wr[3], a.w, s);
            s = fmaf(wr[4], b.x, s); s = fmaf(wr[5], b.y, s);
            s = fmaf(wr[6], b.z, s); s = fmaf(wr[7], b.w, s);
            sums[nd] = s;
        }
    }
    float asv = a_s[lane], adv = a_d[lane];
#pragma unroll
    for (int nd = 0; nd < 16; ++nd) {
        int node = node0 + nd;
        if (node >= n) break;
        float sum = sums[nd];
        h1[(size_t)node * 64 + lane] = sum;
        float vs = sum * asv;
        float vd = sum * adv;
        vs += __shfl_xor(vs, 1); vs += __shfl_xor(vs, 2); vs += __shfl_xor(vs, 4);
        vd += __shfl_xor(vd, 1); vd += __shfl_xor(vd, 2); vd += __shfl_xor(vd, 4);
        if ((lane & 7) == 0) {
            als[(size_t)node * 8 + (lane >> 3)] = vs;
            ald[(size_t)node * 8 + (lane >> 3)] = vd;
        }
    }
}

// GAT layer-1 aggregation: online softmax per dst node, 8 heads x 8 channels.
__global__ void agg1_kernel(const int* __restrict__ row_off, const int* __restrict__ deg,
                            const int2* __restrict__ csr_pair,
                            const float* __restrict__ h1, const float* __restrict__ als,
                            const float* __restrict__ ald, const float* __restrict__ b1,
                            float* __restrict__ helu, int n) {
    int wid = (blockIdx.x << 2) + (threadIdx.x >> 6);
    int lane = threadIdx.x & 63;
    if (wid >= n) return;
    int head = lane >> 3;
    int off = row_off[wid];
    int cnt = deg[wid];
    float aldv = ald[(size_t)wid * 8 + head];
    float m = -1e30f, d = 0.f, accv = 0.f;
    for (int base = 0; base < cnt; base += 64) {
        int nb = min(64, cnt - base);
        int srcv = 0;
        if (lane < nb) srcv = csr_pair[off + base + lane].x;
        for (int tt = 0; tt < nb; ++tt) {
            int s = __builtin_amdgcn_readlane(srcv, tt);
            float e = als[(size_t)s * 8 + head] + aldv;
            e = e > 0.f ? e : 0.2f * e;  // leaky relu
            float hv = h1[(size_t)s * 64 + lane];
            float mn = fmaxf(m, e);
            float scale = __expf(m - mn);
            float p = __expf(e - mn);
            d = fmaf(d, scale, p);
            accv = fmaf(accv, scale, p * hv);
            m = mn;
        }
    }
    float outv = accv / d + b1[lane];
    outv = outv > 0.f ? outv : expm1f(outv);  // ELU
    helu[(size_t)wid * 64 + lane] = outv;
}

// h2 = helu @ W2 (64x40) tiled like gemm1; fused scalar attention logits.
__global__ __launch_bounds__(256) void gemm2_kernel(
    const float* __restrict__ helu, const float* __restrict__ W2,
    const float* __restrict__ a_s, const float* __restrict__ a_d,
    float* __restrict__ h2, float* __restrict__ als, float* __restrict__ ald, int n) {
    __shared__ float Wl[64 * 40];
    __shared__ float Al[4][16 * 64];
    for (int i = threadIdx.x; i < 64 * 40; i += 256) Wl[i] = W2[i];
    int w = threadIdx.x >> 6;
    int lane = threadIdx.x & 63;
    int node0 = (blockIdx.x * 4 + w) * 16;
    const float4* hv4 = (const float4*)helu;
    float4* Av4 = (float4*)Al[w];
#pragma unroll
    for (int i = 0; i < 4; ++i) {
        int f4 = i * 64 + lane;            // 0..255 (16 rows x 16 float4)
        int g4 = node0 * 16 + f4;
        float4 v = (g4 < n * 16) ? hv4[g4] : make_float4(0.f, 0.f, 0.f, 0.f);
        Av4[f4] = v;
    }
    __syncthreads();
    bool act = lane < 40;
    int li = act ? lane : 0;
    float sums[16];
#pragma unroll
    for (int nd = 0; nd < 16; ++nd) sums[nd] = 0.f;
#pragma unroll 1
    for (int kc = 0; kc < 8; ++kc) {
        float wr[8];
#pragma unroll
        for (int i = 0; i < 8; ++i) wr[i] = Wl[(kc * 8 + i) * 40 + li];
#pragma unroll
        for (int nd = 0; nd < 16; ++nd) {
            float4 a = *(const float4*)&Al[w][nd * 64 + kc * 8];
            float4 b = *(const float4*)&Al[w][nd * 64 + kc * 8 + 4];
            float s = sums[nd];
            s = fmaf(wr[0], a.x, s); s = fmaf(wr[1], a.y, s);
            s = fmaf(wr[2], a.z, s); s = fmaf(wr[3], a.w, s);
            s = fmaf(wr[4], b.x, s); s = fmaf(wr[5], b.y, s);
            s = fmaf(wr[6], b.z, s); s = fmaf(wr[7], b.w, s);
            sums[nd] = s;
        }
    }
    float asv = act ? a_s[lane] : 0.f;
    float adv = act ? a_d[lane] : 0.f;
#pragma unroll
    for (int nd = 0; nd < 16; ++nd) {
        int node = node0 + nd;
        if (node >= n) break;
        float sum = sums[nd];
        if (act) h2[(size_t)node * 40 + lane] = sum;
        float vs = act ? sum * asv : 0.f;
        float vd = act ? sum * adv : 0.f;
#pragma unroll
        for (int i = 32; i >= 1; i >>= 1) { vs += __shfl_xor(vs, i); vd += __shfl_xor(vd, i); }
        if (lane == 0) { als[node] = vs; ald[node] = vd; }
    }
}

// GAT layer-2 aggregation (1 head, 40 ch) + bias + log_softmax.
__global__ void agg2_kernel(const int* __restrict__ row_off, const int* __restrict__ deg,
                            const int2* __restrict__ csr_pair,
                            const float* __restrict__ h2, const float* __restrict__ als,
                            const float* __restrict__ ald, const float* __restrict__ b2,
                            float* __restrict__ out, int n) {
    int wid = (blockIdx.x << 2) + (threadIdx.x >> 6);
    int lane = threadIdx.x & 63;
    if (wid >= n) return;
    bool act = lane < 40;
    int li = act ? lane : 0;
    int off = row_off[wid];
    int cnt = deg[wid];
    float aldv = ald[wid];
    float m = -1e30f, d = 0.f, accv = 0.f;
    for (int base = 0; base < cnt; base += 64) {
        int nb = min(64, cnt - base);
        int srcv = 0;
        if (lane < nb) srcv = csr_pair[off + base + lane].x;
        for (int tt = 0; tt < nb; ++tt) {
            int s = __builtin_amdgcn_readlane(srcv, tt);
            float e = als[s] + aldv;
            e = e > 0.f ? e : 0.2f * e;
            float hv = h2[(size_t)s * 40 + li];
            float mn = fmaxf(m, e);
            float scale = __expf(m - mn);
            float p = __expf(e - mn);
            d = fmaf(d, scale, p);
            accv = fmaf(accv, scale, p * hv);
            m = mn;
        }
    }
    float o = accv / d + (act ? b2[lane] : 0.f);
    float vv = act ? o : -1e30f;
#pragma unroll
    for (int i = 32; i >= 1; i >>= 1) vv = fmaxf(vv, __shfl_xor(vv, i));
    float ex = act ? __expf(o - vv) : 0.f;
#pragma unroll
    for (int i = 32; i >= 1; i >>= 1) ex += __shfl_xor(ex, i);
    if (act) out[(size_t)wid * 40 + lane] = o - vv - logf(ex);
}

extern "C" void kernel_launch(void* const* d_in, const int* in_sizes, int n_in,
                              void* d_out, int out_size, void* d_ws, size_t ws_size,
                              hipStream_t stream) {
    const float* x    = (const float*)d_in[0];
    const int*   ei   = (const int*)d_in[1];
    const float* t    = (const float*)d_in[2];
    const float* W1   = (const float*)d_in[3];
    const float* a_s1 = (const float*)d_in[4];
    const float* a_d1 = (const float*)d_in[5];
    const float* b1   = (const float*)d_in[6];
    const float* W2   = (const float*)d_in[7];
    const float* a_s2 = (const float*)d_in[8];
    const float* a_d2 = (const float*)d_in[9];
    const float* b2   = (const float*)d_in[10];
    float* out = (float*)d_out;

    const int N = in_sizes[0] / 128;
    const int E = in_sizes[1] / 2;

    char* w = (char*)d_ws;
    auto carve = [&](size_t bytes) {
        void* p = (void*)w;
        w += (bytes + 255) & ~(size_t)255;
        return p;
    };
    int*      deg      = (int*)carve((size_t)N * 4);
    int*      cursor   = (int*)carve((size_t)N * 4);
    int*      row_off  = (int*)carve((size_t)N * 4);
    int*      gcount   = (int*)carve(256);
    float*    dinv     = (float*)carve((size_t)N * 4);
    int2*     csr_pair = (int2*)carve((size_t)(E + N) * 8);
    float*    coefs    = (float*)carve(11 * 128 * 4);
    float*    als1     = (float*)carve((size_t)N * 8 * 4);
    float*    ald1     = (float*)carve((size_t)N * 8 * 4);
    float*    als2     = (float*)carve((size_t)N * 4);
    float*    ald2     = (float*)carve((size_t)N * 4);
    unsigned* hA       = (unsigned*)carve((size_t)N * 64 * 4);  // bf16x2 per uint
    unsigned* hB       = (unsigned*)carve((size_t)N * 64 * 4);
    float*    acc      = (float*)carve((size_t)N * 128 * 4);
    float*    h1       = (float*)carve((size_t)N * 64 * 4);
    float*    helu     = (float*)carve((size_t)N * 64 * 4);
    float*    h2       = (float*)carve((size_t)N * 40 * 4);

    dim3 blk(256);
    int gN = (N + 255) / 256;
    int gE = (E + 255) / 256;
    int gEN = (E + N + 255) / 256;
    int gW = (N + 3) / 4;        // one wave per node, 4 waves/block
    int gT = (N + 63) / 64;      // wave per 16 nodes, 4 waves/block

    init_node_kernel<<<gN, blk, 0, stream>>>(deg, cursor, N);
    hipMemsetAsync(gcount, 0, 4, stream);
    edge_deg_kernel<<<gE, blk, 0, stream>>>(ei + E, deg, E);
    alloc_kernel<<<gN, blk, 0, stream>>>(deg, dinv, row_off, gcount, N);
    scatter_kernel<<<gEN, blk, 0, stream>>>(ei, row_off, cursor, dinv, csr_pair, E, N);
    coef_kernel<<<1, 128, 0, stream>>>(t, coefs);
    init_diff_kernel<<<(N * 32 + 255) / 256, blk, 0, stream>>>(
        (const float4*)x, coefs, (uint2*)hA, (float4*)acc, N * 32);

    unsigned* hc = hA;
    unsigned* hn = hB;
    for (int k = 1; k <= 10; ++k) {
        hop_kernel<<<gW, blk, 0, stream>>>(row_off, deg, csr_pair, hc, hn, (float2*)acc,
                                           (const float2*)(coefs + k * 128), N,
                                           k < 10 ? 1 : 0);
        unsigned* tmp = hc; hc = hn; hn = tmp;
    }

    gemm1_kernel<<<gT, blk, 0, stream>>>(acc, W1, a_s1, a_d1, h1, als1, ald1, N);
    agg1_kernel<<<gW, blk, 0, stream>>>(row_off, deg, csr_pair, h1, als1, ald1, b1, helu, N);
    gemm2_kernel<<<gT, blk, 0, stream>>>(helu, W2, a_s2, a_d2, h2, als2, ald2, N);
    agg2_kernel<<<gW, blk, 0, stream>>>(row_off, deg, csr_pair, h2, als2, ald2, b2, out, N);
}

// Round 9
// 1310.846 us; speedup vs baseline: 4.1489x; 1.0754x over previous
//
#include <hip/hip_runtime.h>
#include <hip/hip_bf16.h>

// ---------------------------------------------------------------------------
// GAT with heat-kernel diffusion preprocessing (GDC-style), MI355X.
// CSR build -> 10x diffusion hops (bf16 h, readlane gather, fp32 accum) ->
// tiled GEMM1 (bf16 h1 out) -> no-max-softmax GAT agg1 (half-wave edge
// parallel) -> ELU -> GEMM2 (bf16 h2 out) -> agg2 -> log_softmax.
// Round 8: agg kernels lose the online-rescale chain (softmax is shift-
// invariant; logits O(1) so raw exp is safe), gain bf16 gathers + half-wave
// edge split. Hop gather unrolled 8-deep.
// ---------------------------------------------------------------------------

static __device__ __forceinline__ unsigned pack_bf16x2(float a, float b) {
    __hip_bfloat162 p(__float2bfloat16(a), __float2bfloat16(b));  // a in low 16
    return *reinterpret_cast<unsigned*>(&p);
}

__global__ void init_node_kernel(int* deg, int* cursor, int n) {
    int i = blockIdx.x * 256 + threadIdx.x;
    if (i < n) { deg[i] = 1; cursor[i] = 0; }  // deg starts at 1 (self loop)
}

__global__ void edge_deg_kernel(const int* __restrict__ dst, int* deg, int E) {
    int e = blockIdx.x * 256 + threadIdx.x;
    if (e < E) atomicAdd(&deg[dst[e]], 1);
}

__global__ void alloc_kernel(const int* __restrict__ deg, float* dinv,
                             int* row_off, int* gcount, int n) {
    int i = blockIdx.x * 256 + threadIdx.x;
    if (i >= n) return;
    int dg = deg[i];
    dinv[i] = rsqrtf((float)dg);
    row_off[i] = atomicAdd(gcount, dg);
}

__global__ void scatter_kernel(const int* __restrict__ ei, const int* __restrict__ row_off,
                               int* cursor, const float* __restrict__ dinv,
                               int2* csr_pair, int E, int n) {
    int e = blockIdx.x * 256 + threadIdx.x;
    if (e >= E + n) return;
    int s, d;
    if (e < E) { s = ei[e]; d = ei[E + e]; } else { s = e - E; d = s; }
    int pos = atomicAdd(&cursor[d], 1);
    int slot = row_off[d] + pos;
    csr_pair[slot] = make_int2(s, __float_as_int(dinv[s] * dinv[d]));
}

// coefs[k][c] = exp(-t_c) * t_c^k / k!
__global__ void coef_kernel(const float* __restrict__ t, float* coefs) {
    int c = threadIdx.x;  // 128 threads
    float tc = t[c];
    float v = expf(-tc);
    coefs[c] = v;
    for (int k = 1; k <= 10; ++k) { v *= tc / (float)k; coefs[k * 128 + c] = v; }
}

__global__ void init_diff_kernel(const float4* __restrict__ x4, const float* __restrict__ coefs,
                                 uint2* __restrict__ h, float4* __restrict__ acc4, int total4) {
    int i = blockIdx.x * 256 + threadIdx.x;
    if (i >= total4) return;
    float4 xv = x4[i];
    h[i] = make_uint2(pack_bf16x2(xv.x, xv.y), pack_bf16x2(xv.z, xv.w));
    const float4 c = *(const float4*)&coefs[(i & 31) * 4];
    acc4[i] = make_float4(c.x * xv.x, c.y * xv.y, c.z * xv.z, c.w * xv.w);
}

// One wave per node, 2 channels/lane (packed bf16x2). Neighbor (src,norm)
// broadcast via v_readlane; 8 gathers in flight, 4 fp32 accumulator pairs.
__global__ void hop_kernel(const int* __restrict__ row_off, const int* __restrict__ deg,
                           const int2* __restrict__ csr_pair,
                           const unsigned* __restrict__ h, unsigned* __restrict__ h_next,
                           float2* __restrict__ acc2, const float2* __restrict__ coefk2,
                           int n, int write_h) {
    int wid = (blockIdx.x << 2) + (threadIdx.x >> 6);
    int lane = threadIdx.x & 63;
    if (wid >= n) return;
    int off = row_off[wid];
    int cnt = deg[wid];
    float2 a0 = {0.f, 0.f}, a1 = {0.f, 0.f}, a2 = {0.f, 0.f}, a3 = {0.f, 0.f};
    for (int base = 0; base < cnt; base += 64) {
        int nb = min(64, cnt - base);
        int2 p = {0, 0};
        if (lane < nb) p = csr_pair[off + base + lane];
        int tt = 0;
        for (; tt + 7 < nb; tt += 8) {
            int s0 = __builtin_amdgcn_readlane(p.x, tt);
            int s1 = __builtin_amdgcn_readlane(p.x, tt + 1);
            int s2 = __builtin_amdgcn_readlane(p.x, tt + 2);
            int s3 = __builtin_amdgcn_readlane(p.x, tt + 3);
            int s4 = __builtin_amdgcn_readlane(p.x, tt + 4);
            int s5 = __builtin_amdgcn_readlane(p.x, tt + 5);
            int s6 = __builtin_amdgcn_readlane(p.x, tt + 6);
            int s7 = __builtin_amdgcn_readlane(p.x, tt + 7);
            float w0 = __int_as_float(__builtin_amdgcn_readlane(p.y, tt));
            float w1 = __int_as_float(__builtin_amdgcn_readlane(p.y, tt + 1));
            float w2 = __int_as_float(__builtin_amdgcn_readlane(p.y, tt + 2));
            float w3 = __int_as_float(__builtin_amdgcn_readlane(p.y, tt + 3));
            float w4 = __int_as_float(__builtin_amdgcn_readlane(p.y, tt + 4));
            float w5 = __int_as_float(__builtin_amdgcn_readlane(p.y, tt + 5));
            float w6 = __int_as_float(__builtin_amdgcn_readlane(p.y, tt + 6));
            float w7 = __int_as_float(__builtin_amdgcn_readlane(p.y, tt + 7));
            unsigned u0 = h[(size_t)s0 * 64 + lane];
            unsigned u1 = h[(size_t)s1 * 64 + lane];
            unsigned u2 = h[(size_t)s2 * 64 + lane];
            unsigned u3 = h[(size_t)s3 * 64 + lane];
            unsigned u4 = h[(size_t)s4 * 64 + lane];
            unsigned u5 = h[(size_t)s5 * 64 + lane];
            unsigned u6 = h[(size_t)s6 * 64 + lane];
            unsigned u7 = h[(size_t)s7 * 64 + lane];
            a0.x = fmaf(w0, __uint_as_float(u0 << 16), a0.x);
            a0.y = fmaf(w0, __uint_as_float(u0 & 0xffff0000u), a0.y);
            a1.x = fmaf(w1, __uint_as_float(u1 << 16), a1.x);
            a1.y = fmaf(w1, __uint_as_float(u1 & 0xffff0000u), a1.y);
            a2.x = fmaf(w2, __uint_as_float(u2 << 16), a2.x);
            a2.y = fmaf(w2, __uint_as_float(u2 & 0xffff0000u), a2.y);
            a3.x = fmaf(w3, __uint_as_float(u3 << 16), a3.x);
            a3.y = fmaf(w3, __uint_as_float(u3 & 0xffff0000u), a3.y);
            a0.x = fmaf(w4, __uint_as_float(u4 << 16), a0.x);
            a0.y = fmaf(w4, __uint_as_float(u4 & 0xffff0000u), a0.y);
            a1.x = fmaf(w5, __uint_as_float(u5 << 16), a1.x);
            a1.y = fmaf(w5, __uint_as_float(u5 & 0xffff0000u), a1.y);
            a2.x = fmaf(w6, __uint_as_float(u6 << 16), a2.x);
            a2.y = fmaf(w6, __uint_as_float(u6 & 0xffff0000u), a2.y);
            a3.x = fmaf(w7, __uint_as_float(u7 << 16), a3.x);
            a3.y = fmaf(w7, __uint_as_float(u7 & 0xffff0000u), a3.y);
        }
        for (; tt < nb; ++tt) {
            int s = __builtin_amdgcn_readlane(p.x, tt);
            float w = __int_as_float(__builtin_amdgcn_readlane(p.y, tt));
            unsigned u = h[(size_t)s * 64 + lane];
            a0.x = fmaf(w, __uint_as_float(u << 16), a0.x);
            a0.y = fmaf(w, __uint_as_float(u & 0xffff0000u), a0.y);
        }
    }
    float2 s;
    s.x = (a0.x + a1.x) + (a2.x + a3.x);
    s.y = (a0.y + a1.y) + (a2.y + a3.y);
    size_t o = (size_t)wid * 64 + lane;
    if (write_h) h_next[o] = pack_bf16x2(s.x, s.y);
    float2 c = coefk2[lane];
    float2 av = acc2[o];
    av.x = fmaf(c.x, s.x, av.x);
    av.y = fmaf(c.y, s.y, av.y);
    acc2[o] = av;
}

// h1 = acc @ W1 (128x64) tiled; h1 stored bf16-packed [N,32] uints.
// kc loop unroll(1): full unroll spilled to scratch (round-4 regression).
__global__ __launch_bounds__(256) void gemm1_kernel(
    const float* __restrict__ acc, const float* __restrict__ W1,
    const float* __restrict__ a_s, const float* __restrict__ a_d,
    unsigned* __restrict__ h1b, float* __restrict__ als, float* __restrict__ ald, int n) {
    __shared__ float Wl[128 * 64];
    __shared__ float Al[4][16 * 128];
    for (int i = threadIdx.x; i < 128 * 64; i += 256) Wl[i] = W1[i];
    int w = threadIdx.x >> 6;
    int lane = threadIdx.x & 63;
    int node0 = (blockIdx.x * 4 + w) * 16;
    const float4* accv4 = (const float4*)acc;
    float4* Av4 = (float4*)Al[w];
#pragma unroll
    for (int i = 0; i < 8; ++i) {
        int f4 = i * 64 + lane;
        int g4 = node0 * 32 + f4;
        float4 v = (g4 < n * 32) ? accv4[g4] : make_float4(0.f, 0.f, 0.f, 0.f);
        Av4[f4] = v;
    }
    __syncthreads();
    float sums[16];
#pragma unroll
    for (int nd = 0; nd < 16; ++nd) sums[nd] = 0.f;
#pragma unroll 1
    for (int kc = 0; kc < 16; ++kc) {
        float wr[8];
#pragma unroll
        for (int i = 0; i < 8; ++i) wr[i] = Wl[(kc * 8 + i) * 64 + lane];
#pragma unroll
        for (int nd = 0; nd < 16; ++nd) {
            float4 a = *(const float4*)&Al[w][nd * 128 + kc * 8];
            float4 b = *(const float4*)&Al[w][nd * 128 + kc * 8 + 4];
            float s = sums[nd];
            s = fmaf(wr[0], a.x, s); s = fmaf(wr[1], a.y, s);
            s = fmaf(wr[2], a.z, s); s = fmaf(wr[3], a.w, s);
            s = fmaf(wr[4], b.x, s); s = fmaf(wr[5], b.y, s);
            s = fmaf(wr[6], b.z, s); s = fmaf(wr[7], b.w, s);
            sums[nd] = s;
        }
    }
    float asv = a_s[lane], adv = a_d[lane];
#pragma unroll
    for (int nd = 0; nd < 16; ++nd) {
        int node = node0 + nd;
        if (node >= n) break;
        float sum = sums[nd];
        float partner = __shfl_xor(sum, 1);
        if ((lane & 1) == 0) h1b[(size_t)node * 32 + (lane >> 1)] = pack_bf16x2(sum, partner);
        float vs = sum * asv;
        float vd = sum * adv;
        vs += __shfl_xor(vs, 1); vs += __shfl_xor(vs, 2); vs += __shfl_xor(vs, 4);
        vd += __shfl_xor(vd, 1); vd += __shfl_xor(vd, 2); vd += __shfl_xor(vd, 4);
        if ((lane & 7) == 0) {
            als[(size_t)node * 8 + (lane >> 3)] = vs;
            ald[(size_t)node * 8 + (lane >> 3)] = vd;
        }
    }
}

// agg1: softmax agg without max subtraction (shift-invariant; logits O(1)).
// Half-wave edge parallelism: lanes 0-31 even edges, 32-63 odd edges; each
// lane owns channel pair (2l, 2l+1) bf16-packed. Combine via shfl_xor(.,32).
__global__ void agg1_kernel(const int* __restrict__ row_off, const int* __restrict__ deg,
                            const int2* __restrict__ csr_pair,
                            const unsigned* __restrict__ h1b, const float* __restrict__ als,
                            const float* __restrict__ ald, const float* __restrict__ b1,
                            float2* __restrict__ helu2, int n) {
    int wid = (blockIdx.x << 2) + (threadIdx.x >> 6);
    int lane = threadIdx.x & 63;
    if (wid >= n) return;
    int half = lane >> 5;
    int l = lane & 31;          // channel pair index
    int head = l >> 2;          // (2l)>>3
    int off = row_off[wid];
    int cnt = deg[wid];
    float aldv = ald[(size_t)wid * 8 + head];
    float dA = 0.f, dB = 0.f;
    float2 aA = {0.f, 0.f}, aB = {0.f, 0.f};
    for (int base = 0; base < cnt; base += 64) {
        int nb = min(64, cnt - base);
        int srcv = 0;
        if (lane < nb) srcv = csr_pair[off + base + lane].x;
        int j = 0;
        for (; j + 3 < nb; j += 4) {
            int sA0 = __builtin_amdgcn_readlane(srcv, j);
            int sA1 = __builtin_amdgcn_readlane(srcv, j + 1);
            int sB0 = __builtin_amdgcn_readlane(srcv, j + 2);
            int sB1 = __builtin_amdgcn_readlane(srcv, j + 3);
            int sA = half ? sA1 : sA0;
            int sB = half ? sB1 : sB0;
            float eA = als[(size_t)sA * 8 + head] + aldv;
            float eB = als[(size_t)sB * 8 + head] + aldv;
            eA = eA > 0.f ? eA : 0.2f * eA;
            eB = eB > 0.f ? eB : 0.2f * eB;
            float pA = __expf(eA);
            float pB = __expf(eB);
            unsigned uA = h1b[(size_t)sA * 32 + l];
            unsigned uB = h1b[(size_t)sB * 32 + l];
            dA += pA; dB += pB;
            aA.x = fmaf(pA, __uint_as_float(uA << 16), aA.x);
            aA.y = fmaf(pA, __uint_as_float(uA & 0xffff0000u), aA.y);
            aB.x = fmaf(pB, __uint_as_float(uB << 16), aB.x);
            aB.y = fmaf(pB, __uint_as_float(uB & 0xffff0000u), aB.y);
        }
        for (; j < nb; j += 2) {
            int s0 = __builtin_amdgcn_readlane(srcv, j);
            int s1 = (j + 1 < nb) ? __builtin_amdgcn_readlane(srcv, j + 1) : -1;
            int s = half ? s1 : s0;
            bool valid = s >= 0;
            int ss = valid ? s : 0;
            float e = als[(size_t)ss * 8 + head] + aldv;
            e = e > 0.f ? e : 0.2f * e;
            float p = valid ? __expf(e) : 0.f;
            unsigned u = h1b[(size_t)ss * 32 + l];
            dA += p;
            aA.x = fmaf(p, __uint_as_float(u << 16), aA.x);
            aA.y = fmaf(p, __uint_as_float(u & 0xffff0000u), aA.y);
        }
    }
    float d = dA + dB;
    float2 accv = make_float2(aA.x + aB.x, aA.y + aB.y);
    d += __shfl_xor(d, 32);
    accv.x += __shfl_xor(accv.x, 32);
    accv.y += __shfl_xor(accv.y, 32);
    if (half == 0) {
        float inv = 1.f / d;   // d >= exp(self-loop logit) > 0
        float ox = fmaf(accv.x, inv, b1[2 * l]);
        float oy = fmaf(accv.y, inv, b1[2 * l + 1]);
        ox = ox > 0.f ? ox : expm1f(ox);  // ELU
        oy = oy > 0.f ? oy : expm1f(oy);
        helu2[(size_t)wid * 32 + l] = make_float2(ox, oy);
    }
}

// h2 = helu @ W2 (64x40) tiled; h2 stored bf16-packed [N,20] uints.
__global__ __launch_bounds__(256) void gemm2_kernel(
    const float* __restrict__ helu, const float* __restrict__ W2,
    const float* __restrict__ a_s, const float* __restrict__ a_d,
    unsigned* __restrict__ h2b, float* __restrict__ als, float* __restrict__ ald, int n) {
    __shared__ float Wl[64 * 40];
    __shared__ float Al[4][16 * 64];
    for (int i = threadIdx.x; i < 64 * 40; i += 256) Wl[i] = W2[i];
    int w = threadIdx.x >> 6;
    int lane = threadIdx.x & 63;
    int node0 = (blockIdx.x * 4 + w) * 16;
    const float4* hv4 = (const float4*)helu;
    float4* Av4 = (float4*)Al[w];
#pragma unroll
    for (int i = 0; i < 4; ++i) {
        int f4 = i * 64 + lane;
        int g4 = node0 * 16 + f4;
        float4 v = (g4 < n * 16) ? hv4[g4] : make_float4(0.f, 0.f, 0.f, 0.f);
        Av4[f4] = v;
    }
    __syncthreads();
    bool act = lane < 40;
    int li = act ? lane : 0;
    float sums[16];
#pragma unroll
    for (int nd = 0; nd < 16; ++nd) sums[nd] = 0.f;
#pragma unroll 1
    for (int kc = 0; kc < 8; ++kc) {
        float wr[8];
#pragma unroll
        for (int i = 0; i < 8; ++i) wr[i] = Wl[(kc * 8 + i) * 40 + li];
#pragma unroll
        for (int nd = 0; nd < 16; ++nd) {
            float4 a = *(const float4*)&Al[w][nd * 64 + kc * 8];
            float4 b = *(const float4*)&Al[w][nd * 64 + kc * 8 + 4];
            float s = sums[nd];
            s = fmaf(wr[0], a.x, s); s = fmaf(wr[1], a.y, s);
            s = fmaf(wr[2], a.z, s); s = fmaf(wr[3], a.w, s);
            s = fmaf(wr[4], b.x, s); s = fmaf(wr[5], b.y, s);
            s = fmaf(wr[6], b.z, s); s = fmaf(wr[7], b.w, s);
            sums[nd] = s;
        }
    }
    float asv = act ? a_s[lane] : 0.f;
    float adv = act ? a_d[lane] : 0.f;
#pragma unroll
    for (int nd = 0; nd < 16; ++nd) {
        int node = node0 + nd;
        if (node >= n) break;
        float sum = sums[nd];
        float partner = __shfl_xor(sum, 1);
        if (act && (lane & 1) == 0) h2b[(size_t)node * 20 + (lane >> 1)] = pack_bf16x2(sum, partner);
        float vs = act ? sum * asv : 0.f;
        float vd = act ? sum * adv : 0.f;
#pragma unroll
        for (int i = 32; i >= 1; i >>= 1) { vs += __shfl_xor(vs, i); vd += __shfl_xor(vd, i); }
        if (lane == 0) { als[node] = vs; ald[node] = vd; }
    }
}

// agg2 (1 head, 40 ch) no-max softmax + half-wave edge split + log_softmax.
__global__ void agg2_kernel(const int* __restrict__ row_off, const int* __restrict__ deg,
                            const int2* __restrict__ csr_pair,
                            const unsigned* __restrict__ h2b, const float* __restrict__ als,
                            const float* __restrict__ ald, const float* __restrict__ b2,
                            float* __restrict__ out, int n) {
    int wid = (blockIdx.x << 2) + (threadIdx.x >> 6);
    int lane = threadIdx.x & 63;
    if (wid >= n) return;
    int half = lane >> 5;
    int l = lane & 31;
    bool act = l < 20;          // channel pairs 0..19
    int li = act ? l : 0;
    int off = row_off[wid];
    int cnt = deg[wid];
    float aldv = ald[wid];
    float dA = 0.f, dB = 0.f;
    float2 aA = {0.f, 0.f}, aB = {0.f, 0.f};
    for (int base = 0; base < cnt; base += 64) {
        int nb = min(64, cnt - base);
        int srcv = 0;
        if (lane < nb) srcv = csr_pair[off + base + lane].x;
        int j = 0;
        for (; j + 3 < nb; j += 4) {
            int sA0 = __builtin_amdgcn_readlane(srcv, j);
            int sA1 = __builtin_amdgcn_readlane(srcv, j + 1);
            int sB0 = __builtin_amdgcn_readlane(srcv, j + 2);
            int sB1 = __builtin_amdgcn_readlane(srcv, j + 3);
            int sA = half ? sA1 : sA0;
            int sB = half ? sB1 : sB0;
            float eA = als[sA] + aldv;
            float eB = als[sB] + aldv;
            eA = eA > 0.f ? eA : 0.2f * eA;
            eB = eB > 0.f ? eB : 0.2f * eB;
            float pA = __expf(eA);
            float pB = __expf(eB);
            unsigned uA = h2b[(size_t)sA * 20 + li];
            unsigned uB = h2b[(size_t)sB * 20 + li];
            dA += pA; dB += pB;
            aA.x = fmaf(pA, __uint_as_float(uA << 16), aA.x);
            aA.y = fmaf(pA, __uint_as_float(uA & 0xffff0000u), aA.y);
            aB.x = fmaf(pB, __uint_as_float(uB << 16), aB.x);
            aB.y = fmaf(pB, __uint_as_float(uB & 0xffff0000u), aB.y);
        }
        for (; j < nb; j += 2) {
            int s0 = __builtin_amdgcn_readlane(srcv, j);
            int s1 = (j + 1 < nb) ? __builtin_amdgcn_readlane(srcv, j + 1) : -1;
            int s = half ? s1 : s0;
            bool valid = s >= 0;
            int ss = valid ? s : 0;
            float e = als[ss] + aldv;
            e = e > 0.f ? e : 0.2f * e;
            float p = valid ? __expf(e) : 0.f;
            unsigned u = h2b[(size_t)ss * 20 + li];
            dA += p;
            aA.x = fmaf(p, __uint_as_float(u << 16), aA.x);
            aA.y = fmaf(p, __uint_as_float(u & 0xffff0000u), aA.y);
        }
    }
    float d = dA + dB;
    float2 accv = make_float2(aA.x + aB.x, aA.y + aB.y);
    d += __shfl_xor(d, 32);
    accv.x += __shfl_xor(accv.x, 32);
    accv.y += __shfl_xor(accv.y, 32);
    float inv = 1.f / d;
    bool live = (half == 0) && act;
    float ox = live ? fmaf(accv.x, inv, b2[2 * l]) : -1e30f;
    float oy = live ? fmaf(accv.y, inv, b2[2 * l + 1]) : -1e30f;
    // log_softmax over 40 values held 2-per-lane in lanes 0..19 (lower half)
    float vv = fmaxf(ox, oy);
#pragma unroll
    for (int i = 16; i >= 1; i >>= 1) vv = fmaxf(vv, __shfl_xor(vv, i));
    float ex = live ? (__expf(ox - vv) + __expf(oy - vv)) : 0.f;
#pragma unroll
    for (int i = 16; i >= 1; i >>= 1) ex += __shfl_xor(ex, i);
    if (live) {
        float lse = vv + logf(ex);
        *(float2*)&out[(size_t)wid * 40 + 2 * l] = make_float2(ox - lse, oy - lse);
    }
}

extern "C" void kernel_launch(void* const* d_in, const int* in_sizes, int n_in,
                              void* d_out, int out_size, void* d_ws, size_t ws_size,
                              hipStream_t stream) {
    const float* x    = (const float*)d_in[0];
    const int*   ei   = (const int*)d_in[1];
    const float* t    = (const float*)d_in[2];
    const float* W1   = (const float*)d_in[3];
    const float* a_s1 = (const float*)d_in[4];
    const float* a_d1 = (const float*)d_in[5];
    const float* b1   = (const float*)d_in[6];
    const float* W2   = (const float*)d_in[7];
    const float* a_s2 = (const float*)d_in[8];
    const float* a_d2 = (const float*)d_in[9];
    const float* b2   = (const float*)d_in[10];
    float* out = (float*)d_out;

    const int N = in_sizes[0] / 128;
    const int E = in_sizes[1] / 2;

    char* w = (char*)d_ws;
    auto carve = [&](size_t bytes) {
        void* p = (void*)w;
        w += (bytes + 255) & ~(size_t)255;
        return p;
    };
    int*      deg      = (int*)carve((size_t)N * 4);
    int*      cursor   = (int*)carve((size_t)N * 4);
    int*      row_off  = (int*)carve((size_t)N * 4);
    int*      gcount   = (int*)carve(256);
    float*    dinv     = (float*)carve((size_t)N * 4);
    int2*     csr_pair = (int2*)carve((size_t)(E + N) * 8);
    float*    coefs    = (float*)carve(11 * 128 * 4);
    float*    als1     = (float*)carve((size_t)N * 8 * 4);
    float*    ald1     = (float*)carve((size_t)N * 8 * 4);
    float*    als2     = (float*)carve((size_t)N * 4);
    float*    ald2     = (float*)carve((size_t)N * 4);
    unsigned* hA       = (unsigned*)carve((size_t)N * 64 * 4);  // bf16x2 per uint
    unsigned* hB       = (unsigned*)carve((size_t)N * 64 * 4);
    float*    acc      = (float*)carve((size_t)N * 128 * 4);
    unsigned* h1b      = (unsigned*)carve((size_t)N * 32 * 4);  // bf16 [N,64]
    float*    helu     = (float*)carve((size_t)N * 64 * 4);
    unsigned* h2b      = (unsigned*)carve((size_t)N * 20 * 4);  // bf16 [N,40]

    dim3 blk(256);
    int gN = (N + 255) / 256;
    int gE = (E + 255) / 256;
    int gEN = (E + N + 255) / 256;
    int gW = (N + 3) / 4;        // one wave per node, 4 waves/block
    int gT = (N + 63) / 64;      // wave per 16 nodes, 4 waves/block

    init_node_kernel<<<gN, blk, 0, stream>>>(deg, cursor, N);
    hipMemsetAsync(gcount, 0, 4, stream);
    edge_deg_kernel<<<gE, blk, 0, stream>>>(ei + E, deg, E);
    alloc_kernel<<<gN, blk, 0, stream>>>(deg, dinv, row_off, gcount, N);
    scatter_kernel<<<gEN, blk, 0, stream>>>(ei, row_off, cursor, dinv, csr_pair, E, N);
    coef_kernel<<<1, 128, 0, stream>>>(t, coefs);
    init_diff_kernel<<<(N * 32 + 255) / 256, blk, 0, stream>>>(
        (const float4*)x, coefs, (uint2*)hA, (float4*)acc, N * 32);

    unsigned* hc = hA;
    unsigned* hn = hB;
    for (int k = 1; k <= 10; ++k) {
        hop_kernel<<<gW, blk, 0, stream>>>(row_off, deg, csr_pair, hc, hn, (float2*)acc,
                                           (const float2*)(coefs + k * 128), N,
                                           k < 10 ? 1 : 0);
        unsigned* tmp = hc; hc = hn; hn = tmp;
    }

    gemm1_kernel<<<gT, blk, 0, stream>>>(acc, W1, a_s1, a_d1, h1b, als1, ald1, N);
    agg1_kernel<<<gW, blk, 0, stream>>>(row_off, deg, csr_pair, h1b, als1, ald1, b1,
                                        (float2*)helu, N);
    gemm2_kernel<<<gT, blk, 0, stream>>>(helu, W2, a_s2, a_d2, h2b, als2, ald2, N);
    agg2_kernel<<<gW, blk, 0, stream>>>(row_off, deg, csr_pair, h2b, als2, ald2, b2, out, N);
}